// Round 8
// baseline (3638.430 us; speedup 1.0000x reference)
//
#include <hip/hip_runtime.h>
#include <math.h>

// Problem constants
static constexpr int cB = 32;
static constexpr int cT = 1024;
static constexpr int cH = 128;
static constexpr int cD = 256;   // 2H
static constexpr int cN = 2048;  // H*POOL
static constexpr int cM = cB * cT; // 32768

typedef __attribute__((ext_vector_type(8))) short short8;
typedef __attribute__((ext_vector_type(4))) float f32x4;

__device__ __forceinline__ ushort f2bf(float x) {
    union { float f; unsigned u; } v; v.f = x;
    unsigned r = v.u + 0x7FFF + ((v.u >> 16) & 1);   // RNE to bf16
    return (ushort)(r >> 16);
}
__device__ __forceinline__ float bf2f(ushort h) {
    union { float f; unsigned u; } v; v.u = ((unsigned)h) << 16;
    return v.f;
}

// async global->LDS, 16B per lane, wave-uniform LDS base + lane*16
__device__ __forceinline__ void gload_lds16(const ushort* g, ushort* l) {
    __builtin_amdgcn_global_load_lds(
        (const __attribute__((address_space(1))) unsigned int*)(const void*)g,
        (__attribute__((address_space(3))) unsigned int*)(void*)l,
        16, 0, 0);
}

// ---------------------------------------------------------------------------
// Split-bf16 MFMA GEMM, barrier-free k-loop:
//   per 128-k half: stage B half-panel (128 cols x 128 k, hi/lo = 64KB) into
//   LDS ONCE via global_load_lds (XOR pre-swizzled source), one barrier,
//   then 4 k-steps of { A-frags direct from global -> regs, ds_read B, MFMA }
//   with NO barriers / NO LDS writes — compiler pipelines A-loads freely and
//   waves slip (round 6/7 showed per-k-step barriers serialize everything:
//   MfmaUtil 20%, stage+drain+barrier on the critical path).
// A: bf16 hi/lo [M][K] row-major, L2-resident per-XCD (grid swizzle).
// B: bf16 hi/lo transposed [N][K]. 3-term split ah*bh+ah*bl+al*bh, fp32 acc.
// Block 256 thr = 4 waves (2x2), tile 128x128, wave tile 64x64 (4x4 frags).
// LDS B swizzle (T21 both-sides): chunk ck (16B) of col n stored at slot
// ck^(n&7); staged with linear LDS dest + pre-swizzled GLOBAL source;
// ds_read applies the same XOR -> 16 lanes span 8 slot-positions (2-way, free).
// 1-D grid 4096, bijective XCD-chunked swizzle (A-panel L2-resident per XCD).
// ---------------------------------------------------------------------------
template<int K, bool POOL, bool WRITE_HL>
__global__ __launch_bounds__(256, 2)
void mfma_gemm(const ushort* __restrict__ Ah, const ushort* __restrict__ Al,
               const ushort* __restrict__ Bth, const ushort* __restrict__ Btl,
               const float* __restrict__ initv, int init_bstride,
               float* __restrict__ out, ushort* __restrict__ outh,
               ushort* __restrict__ outl)
{
    constexpr int KH = K / 128;                   // 128-k halves (1 or 2)
    __shared__ __attribute__((aligned(16))) ushort sBh[128 * 128];  // 32KB
    __shared__ __attribute__((aligned(16))) ushort sBl[128 * 128];  // 32KB

    const int tid  = threadIdx.x;
    const int wave = tid >> 6;
    const int lane = tid & 63;
    const int l15  = lane & 15;
    const int lg   = lane >> 4;         // 0..3 -> k-subchunk within k-step
    const int wr   = wave >> 1;         // wave row (0..1)
    const int wc   = wave & 1;          // wave col (0..1)

    // XCD-chunked bijective remap (gridDim.x = 4096, 8 XCDs, NX = 16)
    const int wg  = blockIdx.x;
    const int lin = (wg & 7) * 512 + (wg >> 3);
    const int bx  = lin & 15;
    const int by  = lin >> 4;
    const int m0  = by * 128;
    const int n0  = bx * 128;
    const int brow = m0 >> 10;          // batch row (T=1024)

    float iv[4] = {0.f, 0.f, 0.f, 0.f};
    if (initv) {
        #pragma unroll
        for (int nf = 0; nf < 4; ++nf)
            iv[nf] = initv[(size_t)brow * init_bstride + n0 + wc * 64 + nf * 16 + l15];
    }

    f32x4 acc[4][4];
    #pragma unroll
    for (int mf = 0; mf < 4; ++mf)
        #pragma unroll
        for (int nf = 0; nf < 4; ++nf)
            acc[mf][nf] = (f32x4){0.f, 0.f, 0.f, 0.f};

    // staging geometry: per plane 32 wave-instrs of 1KB; wave w does j=0..7.
    // instr i: LDS elems [i*512, i*512+512) = cols i*4..i*4+3, slots 0..15.
    // lane -> col = i*4 + (lane>>4), slot = lane&15; fetch global chunk
    // ck = slot ^ (col&7) of that col.
    const int st_col_lo = lane >> 4;    // 0..3
    const int st_slot   = lane & 15;

    #pragma unroll
    for (int kh = 0; kh < KH; ++kh) {
        const int khb = kh * 128;
        if (kh > 0) __syncthreads();    // protect LDS reuse before restage

        #pragma unroll
        for (int j = 0; j < 8; ++j) {
            int i   = wave * 8 + j;             // 0..31
            int col = i * 4 + st_col_lo;        // 0..127
            int ck  = st_slot ^ (col & 7);      // logical 16B chunk (k/8)
            size_t goff = (size_t)(n0 + col) * K + khb + ck * 8;
            gload_lds16(Bth + goff, sBh + i * 512);
            gload_lds16(Btl + goff, sBl + i * 512);
        }
        __syncthreads();                // drains vmcnt -> B half valid

        // ---- 4 barrier-free k-steps over this half ------------------------
        #pragma unroll
        for (int ks = 0; ks < 4; ++ks) {
            const int kg = khb + ks * 32;

            // A frags direct from global (L2-resident chunk)
            short8 a_h[4], a_l[4];
            #pragma unroll
            for (int mf = 0; mf < 4; ++mf) {
                size_t off = (size_t)(m0 + wr * 64 + mf * 16 + l15) * K + kg + lg * 8;
                a_h[mf] = *(const short8*)(Ah + off);
                a_l[mf] = *(const short8*)(Al + off);
            }
            // B frags from LDS (swizzled)
            short8 b_h[4], b_l[4];
            #pragma unroll
            for (int nf = 0; nf < 4; ++nf) {
                int col = wc * 64 + nf * 16 + l15;
                int ck  = ks * 4 + lg;                       // chunk in half
                int adr = col * 128 + ((ck ^ (col & 7)) * 8);
                b_h[nf] = *(const short8*)(sBh + adr);
                b_l[nf] = *(const short8*)(sBl + adr);
            }

            #pragma unroll
            for (int mf = 0; mf < 4; ++mf)
                #pragma unroll
                for (int nf = 0; nf < 4; ++nf) {
                    acc[mf][nf] = __builtin_amdgcn_mfma_f32_16x16x32_bf16(
                        a_h[mf], b_h[nf], acc[mf][nf], 0, 0, 0);
                    acc[mf][nf] = __builtin_amdgcn_mfma_f32_16x16x32_bf16(
                        a_h[mf], b_l[nf], acc[mf][nf], 0, 0, 0);
                    acc[mf][nf] = __builtin_amdgcn_mfma_f32_16x16x32_bf16(
                        a_l[mf], b_h[nf], acc[mf][nf], 0, 0, 0);
                }
        }
    }

    if (POOL) {
        const int NP = 128;
        #pragma unroll
        for (int mf = 0; mf < 4; ++mf)
            #pragma unroll
            for (int nf = 0; nf < 4; ++nf)
                #pragma unroll
                for (int r = 0; r < 4; ++r) {
                    float v = acc[mf][nf][r] + iv[nf];
                    v = fmaxf(v, __shfl_xor(v, 1));
                    v = fmaxf(v, __shfl_xor(v, 2));
                    v = fmaxf(v, __shfl_xor(v, 4));
                    v = fmaxf(v, __shfl_xor(v, 8));
                    if (l15 == nf) {
                        int row = m0 + wr * 64 + mf * 16 + lg * 4 + r;
                        int col = ((n0 + wc * 64) >> 4) + nf;
                        size_t o = (size_t)row * NP + col;
                        out[o] = v;
                        if (WRITE_HL) {
                            ushort hbb = f2bf(v);
                            outh[o] = hbb;
                            outl[o] = f2bf(v - bf2f(hbb));
                        }
                    }
                }
    } else {
        #pragma unroll
        for (int mf = 0; mf < 4; ++mf)
            #pragma unroll
            for (int nf = 0; nf < 4; ++nf) {
                int col = n0 + wc * 64 + nf * 16 + l15;
                #pragma unroll
                for (int r = 0; r < 4; ++r) {
                    int row = m0 + wr * 64 + mf * 16 + lg * 4 + r;
                    out[(size_t)row * cN + col] = acc[mf][nf][r] + iv[nf];
                }
            }
    }
}

// ---------------------------------------------------------------------------
// m1[m][o] = max_p( A1[m][o*16+p] + rterm[b][o*16+p] ), also emits bf16 hi/lo
// ---------------------------------------------------------------------------
__global__ void m1_from_a1_kernel(const float* __restrict__ A1,
                                  const float* __restrict__ rterm,
                                  float* __restrict__ m1,
                                  ushort* __restrict__ m1h,
                                  ushort* __restrict__ m1l)
{
    int idx = blockIdx.x * 256 + threadIdx.x;   // [0, 32768*128)
    int m = idx >> 7;
    int o = idx & 127;
    int b = m >> 10;
    const float4* a  = (const float4*)(A1 + (size_t)m * cN + o * 16);
    const float4* rt = (const float4*)(rterm + (size_t)b * cN + o * 16);
    float mx = -3.4e38f;
    #pragma unroll
    for (int q = 0; q < 4; ++q) {
        float4 av = a[q];
        float4 rv = rt[q];
        mx = fmaxf(mx, fmaxf(fmaxf(av.x + rv.x, av.y + rv.y),
                             fmaxf(av.z + rv.z, av.w + rv.w)));
    }
    m1[idx] = mx;
    ushort hb = f2bf(mx);
    m1h[idx] = hb;
    m1l[idx] = f2bf(mx - bf2f(hb));
}

// ---------------------------------------------------------------------------
// Weight transpose + bf16 split: W[K x N] row-major -> Wt hi/lo [N][K]
// ---------------------------------------------------------------------------
__global__ void wsplit_kernel(const float* __restrict__ W, int K, int N,
                              ushort* __restrict__ th, ushort* __restrict__ tl)
{
    int idx = blockIdx.x * 256 + threadIdx.x;
    if (idx >= K * N) return;
    int k = idx / N, n = idx - k * N;      // coalesced read
    float x = W[idx];
    ushort h = f2bf(x);
    th[(size_t)n * K + k] = h;
    tl[(size_t)n * K + k] = f2bf(x - bf2f(h));
}

// ---------------------------------------------------------------------------
// U split: U fp32 [M][256] -> Uh/Ul bf16 same layout
// ---------------------------------------------------------------------------
__global__ void usplit_kernel(const float* __restrict__ U,
                              ushort* __restrict__ uh, ushort* __restrict__ ul)
{
    int idx = blockIdx.x * 256 + threadIdx.x;   // cM*cD threads
    float x = U[idx];
    ushort h = f2bf(x);
    uh[idx] = h;
    ul[idx] = f2bf(x - bf2f(h));
}

// ---------------------------------------------------------------------------
// r[b][j] = tanh( concat([h,us,ue])[b] . WDw[:,j] + WDb[j] )
// ---------------------------------------------------------------------------
__global__ void r_kernel(const float* __restrict__ h, const float* __restrict__ us,
                         const float* __restrict__ ue,
                         const float* __restrict__ WDw, const float* __restrict__ WDb,
                         float* __restrict__ r)
{
    int b = blockIdx.x;
    int j = threadIdx.x;  // 128 threads
    __shared__ float x[640];
    x[j]       = h[b * cH + j];
    x[128 + j] = us[b * cD + j];
    x[256 + j] = us[b * cD + 128 + j];
    x[384 + j] = ue[b * cD + j];
    x[512 + j] = ue[b * cD + 128 + j];
    __syncthreads();
    float s = WDb[j];
    for (int k = 0; k < 640; ++k) s = fmaf(x[k], WDw[(size_t)k * cH + j], s);
    r[b * cH + j] = tanhf(s);
}

// ---------------------------------------------------------------------------
// rterm[b][n] = r[b] . W1r[:,n] + W1b[n]    (W1r = rows 256..383 of W1w)
// ---------------------------------------------------------------------------
__global__ void rterm_kernel(const float* __restrict__ r, const float* __restrict__ W1r,
                             const float* __restrict__ W1b, float* __restrict__ rterm)
{
    int b = blockIdx.y;
    int n = blockIdx.x * 256 + threadIdx.x;  // grid (8,32)
    __shared__ float rs[128];
    if (threadIdx.x < 128) rs[threadIdx.x] = r[b * cH + threadIdx.x];
    __syncthreads();
    float s = W1b[n];
    for (int k = 0; k < 128; ++k) s = fmaf(rs[k], W1r[(size_t)k * cN + n], s);
    rterm[(size_t)b * cN + n] = s;
}

// ---------------------------------------------------------------------------
// score[m] = max_p( concat([m1,m2])[m] . W3w[:,p] + W3b[p] ) -> ent region
// ---------------------------------------------------------------------------
__global__ __launch_bounds__(256)
void score_kernel(const float* __restrict__ m1, const float* __restrict__ m2,
                  const float* __restrict__ W3w, const float* __restrict__ W3b,
                  float* __restrict__ ent)
{
    __shared__ float xs[16][257];
    __shared__ float wsh[256 * 16];
    int tid = threadIdx.x;
    int m0 = blockIdx.x * 16;
    #pragma unroll
    for (int q = 0; q < 16; ++q) wsh[tid + q * 256] = W3w[tid + q * 256];
    #pragma unroll
    for (int q = 0; q < 8; ++q) {
        int f = tid + q * 256;
        int rl = f >> 7, col = f & 127;
        xs[rl][col]       = m1[(size_t)(m0 + rl) * cH + col];
        xs[rl][128 + col] = m2[(size_t)(m0 + rl) * cH + col];
    }
    __syncthreads();
    int rl = tid >> 4, p = tid & 15;
    float s = W3b[p];
    for (int k = 0; k < 256; ++k) s = fmaf(xs[rl][k], wsh[k * 16 + p], s);
    #pragma unroll
    for (int off = 8; off; off >>= 1) s = fmaxf(s, __shfl_xor(s, off));
    if (p == 0) ent[m0 + rl] = s;
}

// ---------------------------------------------------------------------------
// argmax over T per batch (first-occurrence ties), write float index,
// gather U row into us/ue
// ---------------------------------------------------------------------------
__global__ void argmax_kernel(const float* __restrict__ sc, const float* __restrict__ U,
                              float* __restrict__ uvec, float* __restrict__ outidx)
{
    int b = blockIdx.x;
    int tid = threadIdx.x;  // 256
    float bv = -3.4e38f;
    int bi = 0x7fffffff;
    for (int t = tid; t < cT; t += 256) {
        float v = sc[b * cT + t];
        if (v > bv || (v == bv && t < bi)) { bv = v; bi = t; }
    }
    __shared__ float vs[256];
    __shared__ int   is[256];
    vs[tid] = bv; is[tid] = bi;
    __syncthreads();
    for (int s = 128; s > 0; s >>= 1) {
        if (tid < s) {
            if (vs[tid + s] > vs[tid] ||
                (vs[tid + s] == vs[tid] && is[tid + s] < is[tid])) {
                vs[tid] = vs[tid + s];
                is[tid] = is[tid + s];
            }
        }
        __syncthreads();
    }
    int best = is[0];
    if (tid == 0) outidx[b] = (float)best;
    uvec[b * cD + tid % cD] = U[((size_t)b * cT + best) * cD + (tid % cD)];
}

// ---------------------------------------------------------------------------
// LSTM cell
// ---------------------------------------------------------------------------
__global__ void lstm_kernel(const float* __restrict__ us, const float* __restrict__ ue,
                            float* __restrict__ h, float* __restrict__ c,
                            const float* __restrict__ wih, const float* __restrict__ whh,
                            const float* __restrict__ bih, const float* __restrict__ bhh)
{
    int b = blockIdx.x;
    int j = threadIdx.x;  // 128
    __shared__ float x[512];
    __shared__ float hh[128];
    x[j]       = us[b * cD + j];
    x[128 + j] = us[b * cD + 128 + j];
    x[256 + j] = ue[b * cD + j];
    x[384 + j] = ue[b * cD + 128 + j];
    hh[j] = h[b * cH + j];
    __syncthreads();
    float g4[4];
    #pragma unroll
    for (int gi = 0; gi < 4; ++gi) {
        int row = gi * 128 + j;
        float s = bih[row] + bhh[row];
        const float* wr = wih + (size_t)row * 512;
        for (int k = 0; k < 512; ++k) s = fmaf(x[k], wr[k], s);
        const float* wr2 = whh + (size_t)row * 128;
        for (int k = 0; k < 128; ++k) s = fmaf(hh[k], wr2[k], s);
        g4[gi] = s;
    }
    float i_ = 1.f / (1.f + expf(-g4[0]));
    float f_ = 1.f / (1.f + expf(-g4[1]));
    float g_ = tanhf(g4[2]);
    float o_ = 1.f / (1.f + expf(-g4[3]));
    float c2 = f_ * c[b * cH + j] + i_ * g_;
    float h2 = o_ * tanhf(c2);
    c[b * cH + j] = c2;
    h[b * cH + j] = h2;
}

__global__ void init_kernel(const float* __restrict__ U, float* __restrict__ us,
                            float* __restrict__ ue, float* __restrict__ h,
                            float* __restrict__ c)
{
    int i = blockIdx.x * 256 + threadIdx.x;  // 8192 threads
    if (i < cB * cD) {
        int b = i >> 8, d = i & 255;
        us[i] = U[((size_t)b * cT + 0) * cD + d];
        ue[i] = U[((size_t)b * cT + 1) * cD + d];
    }
    if (i < cB * cH) { h[i] = 0.f; c[i] = 0.f; }
}

// ---------------------------------------------------------------------------
extern "C" void kernel_launch(void* const* d_in, const int* in_sizes, int n_in,
                              void* d_out, int out_size, void* d_ws, size_t ws_size,
                              hipStream_t stream)
{
    const float* U = (const float*)d_in[0];
    const float* WD_w[2] = {(const float*)d_in[1], (const float*)d_in[9]};
    const float* WD_b[2] = {(const float*)d_in[2], (const float*)d_in[10]};
    const float* W1_w[2] = {(const float*)d_in[3], (const float*)d_in[11]};
    const float* W1_b[2] = {(const float*)d_in[4], (const float*)d_in[12]};
    const float* W2_w[2] = {(const float*)d_in[5], (const float*)d_in[13]};
    const float* W2_b[2] = {(const float*)d_in[6], (const float*)d_in[14]};
    const float* W3_w[2] = {(const float*)d_in[7], (const float*)d_in[15]};
    const float* W3_b[2] = {(const float*)d_in[8], (const float*)d_in[16]};
    const float* wih = (const float*)d_in[17];
    const float* whh = (const float*)d_in[18];
    const float* bih = (const float*)d_in[19];
    const float* bhh = (const float*)d_in[20];

    float* ws = (float*)d_ws;
    float* m1 = ws;                               // 4M floats
    float* m2 = m1 + (size_t)cM * cH;             // 4M
    float* us = m2 + (size_t)cM * cH;
    float* ue = us + cB * cD;
    float* h  = ue + cB * cD;
    float* c  = h + cB * cH;
    float* r  = c + cB * cH;
    float* rterm = r + cB * cH;                   // 64K
    float* cur = rterm + (size_t)cB * cN;

    ushort* m1h = (ushort*)cur;                   cur += (size_t)cM * cH / 2;
    ushort* m1l = (ushort*)cur;                   cur += (size_t)cM * cH / 2;
    ushort* Uh  = (ushort*)cur;                   cur += (size_t)cM * cD / 2;
    ushort* Ul  = (ushort*)cur;                   cur += (size_t)cM * cD / 2;
    ushort* W1th[2], *W1tl[2], *W2th[2], *W2tl[2];
    for (int sd = 0; sd < 2; ++sd) {
        W1th[sd] = (ushort*)cur; cur += (size_t)cN * cD / 2;   // [2048][256]
        W1tl[sd] = (ushort*)cur; cur += (size_t)cN * cD / 2;
        W2th[sd] = (ushort*)cur; cur += (size_t)cN * cH / 2;   // [2048][128]
        W2tl[sd] = (ushort*)cur; cur += (size_t)cN * cH / 2;
    }
    float* A1[2];
    A1[0] = cur;
    A1[1] = A1[0] + (size_t)cM * cN;              // 64M floats each
    size_t need = (size_t)(A1[1] - ws) + (size_t)cM * cN;
    bool pre = ws_size >= need * sizeof(float);

    float* outf = (float*)d_out;

    init_kernel<<<32, 256, 0, stream>>>(U, us, ue, h, c);
    usplit_kernel<<<(cM * cD) / 256, 256, 0, stream>>>(U, Uh, Ul);
    for (int sd = 0; sd < 2; ++sd) {
        wsplit_kernel<<<(cD * cN) / 256, 256, 0, stream>>>(
            W1_w[sd], cD, cN, W1th[sd], W1tl[sd]);     // first 256 rows of W1
        wsplit_kernel<<<(cH * cN) / 256, 256, 0, stream>>>(
            W2_w[sd], cH, cN, W2th[sd], W2tl[sd]);
    }

    const int ggrid = (cN / 128) * (cM / 128);   // 4096, 1-D (XCD swizzle inside)
    if (pre) {
        // A1 = U @ W1w[0:256,:] once per weight set (constant across iters)
        for (int sd = 0; sd < 2; ++sd)
            mfma_gemm<256, false, false><<<ggrid, 256, 0, stream>>>(
                Uh, Ul, W1th[sd], W1tl[sd], nullptr, 0, A1[sd], nullptr, nullptr);
    }

    for (int it = 0; it < 4; ++it) {
        for (int sd = 0; sd < 2; ++sd) {
            r_kernel<<<32, 128, 0, stream>>>(h, us, ue, WD_w[sd], WD_b[sd], r);
            rterm_kernel<<<dim3(8, 32), 256, 0, stream>>>(
                r, W1_w[sd] + (size_t)256 * cN, W1_b[sd], rterm);
            if (pre) {
                m1_from_a1_kernel<<<16384, 256, 0, stream>>>(
                    A1[sd], rterm, m1, m1h, m1l);
            } else {
                mfma_gemm<256, true, true><<<ggrid, 256, 0, stream>>>(
                    Uh, Ul, W1th[sd], W1tl[sd], rterm, cN, m1, m1h, m1l);
            }
            // m2 = pool(m1 @ W2 + b2) -> fp32
            mfma_gemm<128, true, false><<<ggrid, 256, 0, stream>>>(
                m1h, m1l, W2th[sd], W2tl[sd], W2_b[sd], 0, m2, nullptr, nullptr);
            float* ent = outf + 64 + (size_t)(it * 2 + sd) * cB * cT;
            score_kernel<<<2048, 256, 0, stream>>>(m1, m2, W3_w[sd], W3_b[sd], ent);
            argmax_kernel<<<32, 256, 0, stream>>>(ent, U, sd ? ue : us,
                                                  outf + (sd ? 32 : 0));
        }
        lstm_kernel<<<32, 128, 0, stream>>>(us, ue, h, c, wih, whh, bih, bhh);
    }
}

// Round 9
// 2867.897 us; speedup vs baseline: 1.2687x; 1.2687x over previous
//
#include <hip/hip_runtime.h>
#include <math.h>

// Problem constants
static constexpr int cB = 32;
static constexpr int cT = 1024;
static constexpr int cH = 128;
static constexpr int cD = 256;   // 2H
static constexpr int cN = 2048;  // H*POOL
static constexpr int cM = cB * cT; // 32768

typedef __attribute__((ext_vector_type(8))) short short8;
typedef __attribute__((ext_vector_type(4))) float f32x4;

__device__ __forceinline__ ushort f2bf(float x) {
    union { float f; unsigned u; } v; v.f = x;
    unsigned r = v.u + 0x7FFF + ((v.u >> 16) & 1);   // RNE to bf16
    return (ushort)(r >> 16);
}
__device__ __forceinline__ float bf2f(ushort h) {
    union { float f; unsigned u; } v; v.u = ((unsigned)h) << 16;
    return v.f;
}

// async global->LDS, 16B per lane, wave-uniform LDS base + lane*16
__device__ __forceinline__ void gload_lds16(const ushort* g, ushort* l) {
    __builtin_amdgcn_global_load_lds(
        (const __attribute__((address_space(1))) unsigned int*)(const void*)g,
        (__attribute__((address_space(3))) unsigned int*)(void*)l,
        16, 0, 0);
}

// ---------------------------------------------------------------------------
// SWAPPED pooled GEMM:  out[m][o] = max_{p<16}( sum_k X[m][k]*Wt[16o+p][k]
//                                               + initv[ib][n=16o+p] )
// computed as C^T via mfma(Wfrag, Xfrag): D row = n (in lg*4+reg), col = m
// (lane&15)  ->  pool over n = 3 in-lane fmax + shfl_xor(16,32): ~5x cheaper
// epilogue than pooling across lanes (rounds 6-8: epilogue ~= main loop).
// Wt chunk (128 n x 128 k, hi/lo = 64KB) staged in LDS per 128-k half;
// ALL X frags for the half hoisted into regs (32 loads in flight) BEFORE the
// single barrier -> k-loop has zero global-memory waits (rounds 6-8: per-
// k-step L2 latency was the stall). 3-term split ah*bh+ah*bl+al*bh, fp32 acc.
// Block 256thr = 4 waves (2x2: wr = n-half, wc = m-half), tile 128n x 128m.
// 1-D grid 4096, bijective XCD-chunked remap (X m-chunk L2-resident).
// LDS swizzle: slot s of row r holds chunk s^(r&7) (source-side), read
// applies same XOR -> ~2-way conflicts.
// ---------------------------------------------------------------------------
template<int K, bool WRITE_HL>
__global__ __launch_bounds__(256, 2)
void mfma_pool_swp(const ushort* __restrict__ Wth, const ushort* __restrict__ Wtl,
                   const ushort* __restrict__ Xh, const ushort* __restrict__ Xl,
                   const float* __restrict__ initv, int init_bstride,
                   float* __restrict__ out, ushort* __restrict__ outh,
                   ushort* __restrict__ outl)
{
    constexpr int KH = K / 128;
    __shared__ __attribute__((aligned(16))) ushort sWh[128 * 128];  // 32KB
    __shared__ __attribute__((aligned(16))) ushort sWl[128 * 128];  // 32KB

    const int tid  = threadIdx.x;
    const int wave = tid >> 6;
    const int lane = tid & 63;
    const int l15  = lane & 15;
    const int lg   = lane >> 4;
    const int wr   = wave >> 1;         // n-half
    const int wc   = wave & 1;          // m-half

    const int wg  = blockIdx.x;
    const int lin = (wg & 7) * 512 + (wg >> 3);
    const int bx  = lin & 15;           // n block (2048/128)
    const int by  = lin >> 4;           // m block (32768/128)
    const int n0  = bx * 128;
    const int m0  = by * 128;
    const size_t ibase = (size_t)(m0 >> 10) * init_bstride;

    // init values per (rf, r): n = n0 + wr*64 + rf*16 + lg*4 + r
    float ivv[4][4];
    #pragma unroll
    for (int rf = 0; rf < 4; ++rf)
        #pragma unroll
        for (int r = 0; r < 4; ++r)
            ivv[rf][r] = initv[ibase + n0 + wr * 64 + rf * 16 + lg * 4 + r];

    f32x4 acc[4][4];    // [rf(n)][cf(m)]
    #pragma unroll
    for (int rf = 0; rf < 4; ++rf)
        #pragma unroll
        for (int cf = 0; cf < 4; ++cf)
            acc[rf][cf] = (f32x4){0.f, 0.f, 0.f, 0.f};

    const int st_row_lo = lane >> 4;    // 0..3
    const int st_slot   = lane & 15;

    #pragma unroll
    for (int kh = 0; kh < KH; ++kh) {
        const int kb = kh * 128;
        if (kh > 0) __syncthreads();    // all reads of previous half done

        // stage Wt half-chunk: per plane 32 instrs (rows 4i..4i+3)
        #pragma unroll
        for (int j = 0; j < 8; ++j) {
            int i   = wave * 8 + j;             // 0..31
            int row = i * 4 + st_row_lo;        // 0..127
            int ck  = st_slot ^ (row & 7);
            size_t goff = (size_t)(n0 + row) * K + kb + ck * 8;
            gload_lds16(Wth + goff, sWh + i * 512);
            gload_lds16(Wtl + goff, sWl + i * 512);
        }
        // hoist ALL X frags of this half (4 cf x 4 ks, hi/lo = 32 loads)
        short8 xh_[16], xl_[16];
        #pragma unroll
        for (int cf = 0; cf < 4; ++cf)
            #pragma unroll
            for (int ks = 0; ks < 4; ++ks) {
                size_t off = (size_t)(m0 + wc * 64 + cf * 16 + l15) * K
                           + kb + ks * 32 + lg * 8;
                xh_[cf * 4 + ks] = *(const short8*)(Xh + off);
                xl_[cf * 4 + ks] = *(const short8*)(Xl + off);
            }
        __syncthreads();                // drains stage + X loads

        #pragma unroll
        for (int ks = 0; ks < 4; ++ks) {
            short8 w_h[4], w_l[4];
            #pragma unroll
            for (int rf = 0; rf < 4; ++rf) {
                int row  = wr * 64 + rf * 16 + l15;
                int ck2  = ks * 4 + lg;
                int adr  = row * 128 + ((ck2 ^ (row & 7)) * 8);
                w_h[rf] = *(const short8*)(sWh + adr);
                w_l[rf] = *(const short8*)(sWl + adr);
            }
            #pragma unroll
            for (int rf = 0; rf < 4; ++rf)
                #pragma unroll
                for (int cf = 0; cf < 4; ++cf) {
                    acc[rf][cf] = __builtin_amdgcn_mfma_f32_16x16x32_bf16(
                        w_h[rf], xh_[cf * 4 + ks], acc[rf][cf], 0, 0, 0);
                    acc[rf][cf] = __builtin_amdgcn_mfma_f32_16x16x32_bf16(
                        w_l[rf], xh_[cf * 4 + ks], acc[rf][cf], 0, 0, 0);
                    acc[rf][cf] = __builtin_amdgcn_mfma_f32_16x16x32_bf16(
                        w_h[rf], xl_[cf * 4 + ks], acc[rf][cf], 0, 0, 0);
                }
        }
    }

    // epilogue: in-lane pool over reg r + shfl over lg; write from lanes 0-15
    const int NP = 128;
    #pragma unroll
    for (int rf = 0; rf < 4; ++rf) {
        const int o2 = (n0 >> 4) + wr * 4 + rf;
        #pragma unroll
        for (int cf = 0; cf < 4; ++cf) {
            float v0 = acc[rf][cf][0] + ivv[rf][0];
            float v1 = acc[rf][cf][1] + ivv[rf][1];
            float v2 = acc[rf][cf][2] + ivv[rf][2];
            float v3 = acc[rf][cf][3] + ivv[rf][3];
            float mx = fmaxf(fmaxf(v0, v1), fmaxf(v2, v3));
            mx = fmaxf(mx, __shfl_xor(mx, 16));
            mx = fmaxf(mx, __shfl_xor(mx, 32));
            if (lane < 16) {
                int m = m0 + wc * 64 + cf * 16 + lane;
                size_t o = (size_t)m * NP + o2;
                out[o] = mx;
                if (WRITE_HL) {
                    ushort hb = f2bf(mx);
                    outh[o] = hb;
                    outl[o] = f2bf(mx - bf2f(hb));
                }
            }
        }
    }
}

// ---------------------------------------------------------------------------
// A1 GEMM (no pool), K=256: out[m][n] = sum_k U[m][k]*W1t[n][k], fp32 out.
// Same hoisted-load structure; unswapped (coalesced 268MB writes).
// ---------------------------------------------------------------------------
__global__ __launch_bounds__(256, 2)
void mfma_gemm_a1(const ushort* __restrict__ Uh, const ushort* __restrict__ Ul,
                  const ushort* __restrict__ Bth, const ushort* __restrict__ Btl,
                  float* __restrict__ out)
{
    constexpr int K = 256;
    __shared__ __attribute__((aligned(16))) ushort sBh[128 * 128];
    __shared__ __attribute__((aligned(16))) ushort sBl[128 * 128];

    const int tid  = threadIdx.x;
    const int wave = tid >> 6;
    const int lane = tid & 63;
    const int l15  = lane & 15;
    const int lg   = lane >> 4;
    const int wr   = wave >> 1;         // m-half
    const int wc   = wave & 1;          // n-half

    const int wg  = blockIdx.x;
    const int lin = (wg & 7) * 512 + (wg >> 3);
    const int bx  = lin & 15;
    const int by  = lin >> 4;
    const int n0  = bx * 128;
    const int m0  = by * 128;

    f32x4 acc[4][4];    // [mf][nf]
    #pragma unroll
    for (int mf = 0; mf < 4; ++mf)
        #pragma unroll
        for (int nf = 0; nf < 4; ++nf)
            acc[mf][nf] = (f32x4){0.f, 0.f, 0.f, 0.f};

    const int st_row_lo = lane >> 4;
    const int st_slot   = lane & 15;

    #pragma unroll
    for (int kh = 0; kh < 2; ++kh) {
        const int kb = kh * 128;
        if (kh > 0) __syncthreads();

        #pragma unroll
        for (int j = 0; j < 8; ++j) {
            int i   = wave * 8 + j;
            int row = i * 4 + st_row_lo;
            int ck  = st_slot ^ (row & 7);
            size_t goff = (size_t)(n0 + row) * K + kb + ck * 8;
            gload_lds16(Bth + goff, sBh + i * 512);
            gload_lds16(Btl + goff, sBl + i * 512);
        }
        short8 ph[16], pl[16];
        #pragma unroll
        for (int mf = 0; mf < 4; ++mf)
            #pragma unroll
            for (int ks = 0; ks < 4; ++ks) {
                size_t off = (size_t)(m0 + wr * 64 + mf * 16 + l15) * K
                           + kb + ks * 32 + lg * 8;
                ph[mf * 4 + ks] = *(const short8*)(Uh + off);
                pl[mf * 4 + ks] = *(const short8*)(Ul + off);
            }
        __syncthreads();

        #pragma unroll
        for (int ks = 0; ks < 4; ++ks) {
            short8 b_h[4], b_l[4];
            #pragma unroll
            for (int nf = 0; nf < 4; ++nf) {
                int row  = wc * 64 + nf * 16 + l15;
                int ck2  = ks * 4 + lg;
                int adr  = row * 128 + ((ck2 ^ (row & 7)) * 8);
                b_h[nf] = *(const short8*)(sBh + adr);
                b_l[nf] = *(const short8*)(sBl + adr);
            }
            #pragma unroll
            for (int mf = 0; mf < 4; ++mf)
                #pragma unroll
                for (int nf = 0; nf < 4; ++nf) {
                    acc[mf][nf] = __builtin_amdgcn_mfma_f32_16x16x32_bf16(
                        ph[mf * 4 + ks], b_h[nf], acc[mf][nf], 0, 0, 0);
                    acc[mf][nf] = __builtin_amdgcn_mfma_f32_16x16x32_bf16(
                        ph[mf * 4 + ks], b_l[nf], acc[mf][nf], 0, 0, 0);
                    acc[mf][nf] = __builtin_amdgcn_mfma_f32_16x16x32_bf16(
                        pl[mf * 4 + ks], b_h[nf], acc[mf][nf], 0, 0, 0);
                }
        }
    }

    #pragma unroll
    for (int mf = 0; mf < 4; ++mf)
        #pragma unroll
        for (int nf = 0; nf < 4; ++nf) {
            int col = n0 + wc * 64 + nf * 16 + l15;
            #pragma unroll
            for (int r = 0; r < 4; ++r) {
                int row = m0 + wr * 64 + mf * 16 + lg * 4 + r;
                out[(size_t)row * cN + col] = acc[mf][nf][r];
            }
        }
}

// ---------------------------------------------------------------------------
// m1[m][o] = max_p( A1[m][o*16+p] + rterm[b][o*16+p] ), also emits bf16 hi/lo
// ---------------------------------------------------------------------------
__global__ void m1_from_a1_kernel(const float* __restrict__ A1,
                                  const float* __restrict__ rterm,
                                  float* __restrict__ m1,
                                  ushort* __restrict__ m1h,
                                  ushort* __restrict__ m1l)
{
    int idx = blockIdx.x * 256 + threadIdx.x;   // [0, 32768*128)
    int m = idx >> 7;
    int o = idx & 127;
    int b = m >> 10;
    const float4* a  = (const float4*)(A1 + (size_t)m * cN + o * 16);
    const float4* rt = (const float4*)(rterm + (size_t)b * cN + o * 16);
    float mx = -3.4e38f;
    #pragma unroll
    for (int q = 0; q < 4; ++q) {
        float4 av = a[q];
        float4 rv = rt[q];
        mx = fmaxf(mx, fmaxf(fmaxf(av.x + rv.x, av.y + rv.y),
                             fmaxf(av.z + rv.z, av.w + rv.w)));
    }
    m1[idx] = mx;
    ushort hb = f2bf(mx);
    m1h[idx] = hb;
    m1l[idx] = f2bf(mx - bf2f(hb));
}

// ---------------------------------------------------------------------------
// Weight transpose + bf16 split: W[K x N] row-major -> Wt hi/lo [N][K]
// ---------------------------------------------------------------------------
__global__ void wsplit_kernel(const float* __restrict__ W, int K, int N,
                              ushort* __restrict__ th, ushort* __restrict__ tl)
{
    int idx = blockIdx.x * 256 + threadIdx.x;
    if (idx >= K * N) return;
    int k = idx / N, n = idx - k * N;      // coalesced read
    float x = W[idx];
    ushort h = f2bf(x);
    th[(size_t)n * K + k] = h;
    tl[(size_t)n * K + k] = f2bf(x - bf2f(h));
}

// ---------------------------------------------------------------------------
// U split: U fp32 [M][256] -> Uh/Ul bf16 same layout
// ---------------------------------------------------------------------------
__global__ void usplit_kernel(const float* __restrict__ U,
                              ushort* __restrict__ uh, ushort* __restrict__ ul)
{
    int idx = blockIdx.x * 256 + threadIdx.x;   // cM*cD threads
    float x = U[idx];
    ushort h = f2bf(x);
    uh[idx] = h;
    ul[idx] = f2bf(x - bf2f(h));
}

// ---------------------------------------------------------------------------
// r[b][j] = tanh( concat([h,us,ue])[b] . WDw[:,j] + WDb[j] )
// ---------------------------------------------------------------------------
__global__ void r_kernel(const float* __restrict__ h, const float* __restrict__ us,
                         const float* __restrict__ ue,
                         const float* __restrict__ WDw, const float* __restrict__ WDb,
                         float* __restrict__ r)
{
    int b = blockIdx.x;
    int j = threadIdx.x;  // 128 threads
    __shared__ float x[640];
    x[j]       = h[b * cH + j];
    x[128 + j] = us[b * cD + j];
    x[256 + j] = us[b * cD + 128 + j];
    x[384 + j] = ue[b * cD + j];
    x[512 + j] = ue[b * cD + 128 + j];
    __syncthreads();
    float s = WDb[j];
    for (int k = 0; k < 640; ++k) s = fmaf(x[k], WDw[(size_t)k * cH + j], s);
    r[b * cH + j] = tanhf(s);
}

// ---------------------------------------------------------------------------
// rterm[b][n] = r[b] . W1r[:,n] + W1b[n]    (W1r = rows 256..383 of W1w)
// ---------------------------------------------------------------------------
__global__ void rterm_kernel(const float* __restrict__ r, const float* __restrict__ W1r,
                             const float* __restrict__ W1b, float* __restrict__ rterm)
{
    int b = blockIdx.y;
    int n = blockIdx.x * 256 + threadIdx.x;  // grid (8,32)
    __shared__ float rs[128];
    if (threadIdx.x < 128) rs[threadIdx.x] = r[b * cH + threadIdx.x];
    __syncthreads();
    float s = W1b[n];
    for (int k = 0; k < 128; ++k) s = fmaf(rs[k], W1r[(size_t)k * cN + n], s);
    rterm[(size_t)b * cN + n] = s;
}

// ---------------------------------------------------------------------------
// score[m] = max_p( concat([m1,m2])[m] . W3w[:,p] + W3b[p] ) -> ent region
// ---------------------------------------------------------------------------
__global__ __launch_bounds__(256)
void score_kernel(const float* __restrict__ m1, const float* __restrict__ m2,
                  const float* __restrict__ W3w, const float* __restrict__ W3b,
                  float* __restrict__ ent)
{
    __shared__ float xs[16][257];
    __shared__ float wsh[256 * 16];
    int tid = threadIdx.x;
    int m0 = blockIdx.x * 16;
    #pragma unroll
    for (int q = 0; q < 16; ++q) wsh[tid + q * 256] = W3w[tid + q * 256];
    #pragma unroll
    for (int q = 0; q < 8; ++q) {
        int f = tid + q * 256;
        int rl = f >> 7, col = f & 127;
        xs[rl][col]       = m1[(size_t)(m0 + rl) * cH + col];
        xs[rl][128 + col] = m2[(size_t)(m0 + rl) * cH + col];
    }
    __syncthreads();
    int rl = tid >> 4, p = tid & 15;
    float s = W3b[p];
    for (int k = 0; k < 256; ++k) s = fmaf(xs[rl][k], wsh[k * 16 + p], s);
    #pragma unroll
    for (int off = 8; off; off >>= 1) s = fmaxf(s, __shfl_xor(s, off));
    if (p == 0) ent[m0 + rl] = s;
}

// ---------------------------------------------------------------------------
// argmax over T per batch (first-occurrence ties), write float index,
// gather U row into us/ue
// ---------------------------------------------------------------------------
__global__ void argmax_kernel(const float* __restrict__ sc, const float* __restrict__ U,
                              float* __restrict__ uvec, float* __restrict__ outidx)
{
    int b = blockIdx.x;
    int tid = threadIdx.x;  // 256
    float bv = -3.4e38f;
    int bi = 0x7fffffff;
    for (int t = tid; t < cT; t += 256) {
        float v = sc[b * cT + t];
        if (v > bv || (v == bv && t < bi)) { bv = v; bi = t; }
    }
    __shared__ float vs[256];
    __shared__ int   is[256];
    vs[tid] = bv; is[tid] = bi;
    __syncthreads();
    for (int s = 128; s > 0; s >>= 1) {
        if (tid < s) {
            if (vs[tid + s] > vs[tid] ||
                (vs[tid + s] == vs[tid] && is[tid + s] < is[tid])) {
                vs[tid] = vs[tid + s];
                is[tid] = is[tid + s];
            }
        }
        __syncthreads();
    }
    int best = is[0];
    if (tid == 0) outidx[b] = (float)best;
    uvec[b * cD + tid % cD] = U[((size_t)b * cT + best) * cD + (tid % cD)];
}

// ---------------------------------------------------------------------------
// LSTM cell
// ---------------------------------------------------------------------------
__global__ void lstm_kernel(const float* __restrict__ us, const float* __restrict__ ue,
                            float* __restrict__ h, float* __restrict__ c,
                            const float* __restrict__ wih, const float* __restrict__ whh,
                            const float* __restrict__ bih, const float* __restrict__ bhh)
{
    int b = blockIdx.x;
    int j = threadIdx.x;  // 128
    __shared__ float x[512];
    __shared__ float hh[128];
    x[j]       = us[b * cD + j];
    x[128 + j] = us[b * cD + 128 + j];
    x[256 + j] = ue[b * cD + j];
    x[384 + j] = ue[b * cD + 128 + j];
    hh[j] = h[b * cH + j];
    __syncthreads();
    float g4[4];
    #pragma unroll
    for (int gi = 0; gi < 4; ++gi) {
        int row = gi * 128 + j;
        float s = bih[row] + bhh[row];
        const float* wr = wih + (size_t)row * 512;
        for (int k = 0; k < 512; ++k) s = fmaf(x[k], wr[k], s);
        const float* wr2 = whh + (size_t)row * 128;
        for (int k = 0; k < 128; ++k) s = fmaf(hh[k], wr2[k], s);
        g4[gi] = s;
    }
    float i_ = 1.f / (1.f + expf(-g4[0]));
    float f_ = 1.f / (1.f + expf(-g4[1]));
    float g_ = tanhf(g4[2]);
    float o_ = 1.f / (1.f + expf(-g4[3]));
    float c2 = f_ * c[b * cH + j] + i_ * g_;
    float h2 = o_ * tanhf(c2);
    c[b * cH + j] = c2;
    h[b * cH + j] = h2;
}

__global__ void init_kernel(const float* __restrict__ U, float* __restrict__ us,
                            float* __restrict__ ue, float* __restrict__ h,
                            float* __restrict__ c)
{
    int i = blockIdx.x * 256 + threadIdx.x;  // 8192 threads
    if (i < cB * cD) {
        int b = i >> 8, d = i & 255;
        us[i] = U[((size_t)b * cT + 0) * cD + d];
        ue[i] = U[((size_t)b * cT + 1) * cD + d];
    }
    if (i < cB * cH) { h[i] = 0.f; c[i] = 0.f; }
}

// ---------------------------------------------------------------------------
extern "C" void kernel_launch(void* const* d_in, const int* in_sizes, int n_in,
                              void* d_out, int out_size, void* d_ws, size_t ws_size,
                              hipStream_t stream)
{
    const float* U = (const float*)d_in[0];
    const float* WD_w[2] = {(const float*)d_in[1], (const float*)d_in[9]};
    const float* WD_b[2] = {(const float*)d_in[2], (const float*)d_in[10]};
    const float* W1_w[2] = {(const float*)d_in[3], (const float*)d_in[11]};
    const float* W1_b[2] = {(const float*)d_in[4], (const float*)d_in[12]};
    const float* W2_w[2] = {(const float*)d_in[5], (const float*)d_in[13]};
    const float* W2_b[2] = {(const float*)d_in[6], (const float*)d_in[14]};
    const float* W3_w[2] = {(const float*)d_in[7], (const float*)d_in[15]};
    const float* W3_b[2] = {(const float*)d_in[8], (const float*)d_in[16]};
    const float* wih = (const float*)d_in[17];
    const float* whh = (const float*)d_in[18];
    const float* bih = (const float*)d_in[19];
    const float* bhh = (const float*)d_in[20];

    float* ws = (float*)d_ws;
    float* m1 = ws;                               // 4M floats
    float* m2 = m1 + (size_t)cM * cH;             // 4M
    float* us = m2 + (size_t)cM * cH;
    float* ue = us + cB * cD;
    float* h  = ue + cB * cD;
    float* c  = h + cB * cH;
    float* r  = c + cB * cH;
    float* rterm = r + cB * cH;                   // 64K
    float* cur = rterm + (size_t)cB * cN;

    ushort* m1h = (ushort*)cur;                   cur += (size_t)cM * cH / 2;
    ushort* m1l = (ushort*)cur;                   cur += (size_t)cM * cH / 2;
    ushort* Uh  = (ushort*)cur;                   cur += (size_t)cM * cD / 2;
    ushort* Ul  = (ushort*)cur;                   cur += (size_t)cM * cD / 2;
    ushort* W1th[2], *W1tl[2], *W2th[2], *W2tl[2];
    for (int sd = 0; sd < 2; ++sd) {
        W1th[sd] = (ushort*)cur; cur += (size_t)cN * cD / 2;   // [2048][256]
        W1tl[sd] = (ushort*)cur; cur += (size_t)cN * cD / 2;
        W2th[sd] = (ushort*)cur; cur += (size_t)cN * cH / 2;   // [2048][128]
        W2tl[sd] = (ushort*)cur; cur += (size_t)cN * cH / 2;
    }
    float* A1[2];
    A1[0] = cur;
    A1[1] = A1[0] + (size_t)cM * cN;              // 64M floats each
    size_t need = (size_t)(A1[1] - ws) + (size_t)cM * cN;
    bool pre = ws_size >= need * sizeof(float);

    float* outf = (float*)d_out;

    init_kernel<<<32, 256, 0, stream>>>(U, us, ue, h, c);
    usplit_kernel<<<(cM * cD) / 256, 256, 0, stream>>>(U, Uh, Ul);
    for (int sd = 0; sd < 2; ++sd) {
        wsplit_kernel<<<(cD * cN) / 256, 256, 0, stream>>>(
            W1_w[sd], cD, cN, W1th[sd], W1tl[sd]);     // first 256 rows of W1
        wsplit_kernel<<<(cH * cN) / 256, 256, 0, stream>>>(
            W2_w[sd], cH, cN, W2th[sd], W2tl[sd]);
    }

    const int ggrid = (cN / 128) * (cM / 128);   // 4096, 1-D (XCD swizzle inside)
    if (pre) {
        // A1 = U @ W1w[0:256,:] once per weight set (constant across iters)
        for (int sd = 0; sd < 2; ++sd)
            mfma_gemm_a1<<<ggrid, 256, 0, stream>>>(
                Uh, Ul, W1th[sd], W1tl[sd], A1[sd]);
    }

    for (int it = 0; it < 4; ++it) {
        for (int sd = 0; sd < 2; ++sd) {
            r_kernel<<<32, 128, 0, stream>>>(h, us, ue, WD_w[sd], WD_b[sd], r);
            rterm_kernel<<<dim3(8, 32), 256, 0, stream>>>(
                r, W1_w[sd] + (size_t)256 * cN, W1_b[sd], rterm);
            if (pre) {
                m1_from_a1_kernel<<<16384, 256, 0, stream>>>(
                    A1[sd], rterm, m1, m1h, m1l);
            } else {
                mfma_pool_swp<256, true><<<ggrid, 256, 0, stream>>>(
                    W1th[sd], W1tl[sd], Uh, Ul, rterm, cN, m1, m1h, m1l);
            }
            // m2 = pool(m1 @ W2 + b2) -> fp32 (swapped orientation)
            mfma_pool_swp<128, false><<<ggrid, 256, 0, stream>>>(
                W2th[sd], W2tl[sd], m1h, m1l, W2_b[sd], 0, m2, nullptr, nullptr);
            float* ent = outf + 64 + (size_t)(it * 2 + sd) * cB * cT;
            score_kernel<<<2048, 256, 0, stream>>>(m1, m2, W3_w[sd], W3_b[sd], ent);
            argmax_kernel<<<32, 256, 0, stream>>>(ent, U, sd ? ue : us,
                                                  outf + (sd ? 32 : 0));
        }
        lstm_kernel<<<32, 128, 0, stream>>>(us, ue, h, c, wih, whh, bih, bhh);
    }
}